// Round 1
// baseline (648.154 us; speedup 1.0000x reference)
//
#include <hip/hip_runtime.h>

// x: [n=8, c=256, t=16, h=56, w=56] fp32, contiguous.
// y[n,c,t,hw] = w[c,0]*x[n,c,t-2,hw] + w[c,1]*x[n,c,t,hw] + w[c,2]*x[n,c,t+2,hw]
// (depthwise conv1d k=3, pad 2, dilation 2 along t; zeros out of range)
//
// Vectorized float4: HW = 56*56 = 3136 = 784 float4 per (n,c,t) plane.
// Shift stride is a whole plane (2*784 vec), so vectors never straddle taps.

#define HW4        784          // float4s per (n,c,t) plane
#define T_DIM      16
#define C_DIM      256
#define TOTAL_VEC  25690112     // 8*256*16*784
#define BLOCK      256

__global__ __launch_bounds__(BLOCK) void tes_shift_kernel(
        const float4* __restrict__ x,
        const float*  __restrict__ wgt,
        float4*       __restrict__ out) {
    int i = blockIdx.x * BLOCK + threadIdx.x;   // < 2^25, int is fine
    int plane = i / HW4;                        // magic-mul division by const
    int t = plane & (T_DIM - 1);
    int c = (plane >> 4) & (C_DIM - 1);

    float w0 = wgt[3 * c + 0];
    float w1 = wgt[3 * c + 1];
    float w2 = wgt[3 * c + 2];

    const float4 zero = make_float4(0.f, 0.f, 0.f, 0.f);
    // Predicate each tap's load on (weight != 0) && in-range. Wave-uniform in
    // the common case (a wave sits inside one plane -> one channel).
    float4 a = (w0 != 0.f && t >= 2)         ? x[i - 2 * HW4] : zero;
    float4 b = (w1 != 0.f)                   ? x[i]           : zero;
    float4 d = (w2 != 0.f && t <= T_DIM - 3) ? x[i + 2 * HW4] : zero;

    float4 y;
    y.x = w0 * a.x + w1 * b.x + w2 * d.x;
    y.y = w0 * a.y + w1 * b.y + w2 * d.y;
    y.z = w0 * a.z + w1 * b.z + w2 * d.z;
    y.w = w0 * a.w + w1 * b.w + w2 * d.w;
    out[i] = y;
}

extern "C" void kernel_launch(void* const* d_in, const int* in_sizes, int n_in,
                              void* d_out, int out_size, void* d_ws, size_t ws_size,
                              hipStream_t stream) {
    const float4* x   = (const float4*)d_in[0];
    const float*  wgt = (const float*)d_in[1];
    float4*       out = (float4*)d_out;
    tes_shift_kernel<<<TOTAL_VEC / BLOCK, BLOCK, 0, stream>>>(x, wgt, out);
}